// Round 1
// baseline (12851.965 us; speedup 1.0000x reference)
//
#include <hip/hip_runtime.h>
#include <hip/hip_bf16.h>
#include <math.h>

#define B_ 256
#define T_ 32
#define D_ 500
#define H_ 1024
#define V_ 8000
#define NF_ 512
#define G3H (3*H_)   // 3072
#define H2 (2*H_)    // 2048
#define OUTC (H_ + 3*NF_ + V_)   // 10560

// ---------------------------------------------------------------------------
// Classical 128x128x8 fp32 GEMM:  C[m,n] = sum_k A[m*lda+k] * B[boff + n*ldbn + k*ldbk]
// mode 0: C[m*ldc + n] = val (+bias[n])
// mode 1 (conv tap): Y[((m>>5)*Tout + (m&31) + s)*NF_ + n] += val
// M, N must be multiples of 128. K arbitrary (guarded loads).
// ---------------------------------------------------------------------------
__global__ __launch_bounds__(256) void gemm128(
    const float* __restrict__ A, int lda,
    const float* __restrict__ Bm, long ldbn, int ldbk, long boff,
    const float* __restrict__ bias,
    float* __restrict__ C, int ldc,
    int K, int mode, int Tout, int sshift)
{
    __shared__ float As[8][128];
    __shared__ float Bs[8][128];
    const int tid  = threadIdx.x;
    const int m0   = blockIdx.y * 128;
    const int n0   = blockIdx.x * 128;
    const int lrow = tid >> 1;          // 0..127
    const int lk4  = (tid & 1) * 4;     // 0 or 4
    const int tx   = tid & 15;
    const int ty   = tid >> 4;

    float acc[8][8];
#pragma unroll
    for (int i = 0; i < 8; ++i)
#pragma unroll
        for (int j = 0; j < 8; ++j) acc[i][j] = 0.f;

    const int nk = (K + 7) >> 3;
    for (int kt = 0; kt < nk; ++kt) {
        const int k0 = kt << 3;
#pragma unroll
        for (int i = 0; i < 4; ++i) {
            int k = k0 + lk4 + i;
            As[lk4 + i][lrow] = (k < K) ? A[(long)(m0 + lrow) * lda + k] : 0.f;
            Bs[lk4 + i][lrow] = (k < K) ? Bm[boff + (long)(n0 + lrow) * ldbn + (long)k * ldbk] : 0.f;
        }
        __syncthreads();
#pragma unroll
        for (int kk = 0; kk < 8; ++kk) {
            float av[8], bv[8];
#pragma unroll
            for (int i = 0; i < 8; ++i) av[i] = As[kk][ty * 8 + i];
#pragma unroll
            for (int j = 0; j < 8; ++j) bv[j] = Bs[kk][tx * 8 + j];
#pragma unroll
            for (int i = 0; i < 8; ++i)
#pragma unroll
                for (int j = 0; j < 8; ++j)
                    acc[i][j] = fmaf(av[i], bv[j], acc[i][j]);
        }
        __syncthreads();
    }

#pragma unroll
    for (int i = 0; i < 8; ++i) {
        const int m = m0 + ty * 8 + i;
#pragma unroll
        for (int j = 0; j < 8; ++j) {
            const int n = n0 + tx * 8 + j;
            float v = acc[i][j];
            if (bias) v += bias[n];
            if (mode == 0) {
                C[(long)m * ldc + n] = v;
            } else {
                const int bb = m >> 5, tt = m & 31;
                C[((long)(bb * Tout + tt + sshift)) * NF_ + n] += v;
            }
        }
    }
}

// ---------------------------------------------------------------------------
// One GRU timestep, fused gates. Computes hg = h_prev @ Whh^T for the 3 gate
// blocks of the output tile, then r/z/n gates, h_next, and the masked output.
// Grid: (H/32, B/32), 256 threads. BK=32 over K=H.
// ---------------------------------------------------------------------------
__global__ __launch_bounds__(256) void gru_step(
    const float* __restrict__ xg, const float* __restrict__ Whh,
    const float* __restrict__ bhh, const float* __restrict__ h_prev,
    float* __restrict__ h_next, float* __restrict__ gout,
    const int* __restrict__ lengths, int tt, int dir)
{
    __shared__ float Hs[32][33], Wr[32][33], Wz[32][33], Wn[32][33];
    const int tid = threadIdx.x;
    const int j0 = blockIdx.x * 32, b0 = blockIdx.y * 32;
    const int tx = tid & 31;        // output h col
    const int ty = tid >> 5;        // 0..7 -> 4 batch rows each

    float ar[4] = {0.f,0.f,0.f,0.f};
    float az[4] = {0.f,0.f,0.f,0.f};
    float an[4] = {0.f,0.f,0.f,0.f};

    for (int k0 = 0; k0 < H_; k0 += 32) {
        for (int i = tid; i < 1024; i += 256) {
            const int r = i >> 5, c = i & 31;
            Hs[r][c] = h_prev[(long)(b0 + r) * H_ + k0 + c];
            Wr[r][c] = Whh[(long)(j0 + r) * H_ + k0 + c];
            Wz[r][c] = Whh[(long)(H_ + j0 + r) * H_ + k0 + c];
            Wn[r][c] = Whh[(long)(2 * H_ + j0 + r) * H_ + k0 + c];
        }
        __syncthreads();
        for (int c = 0; c < 32; ++c) {
            const float wr = Wr[tx][c], wz = Wz[tx][c], wn = Wn[tx][c];
#pragma unroll
            for (int i = 0; i < 4; ++i) {
                const float hv = Hs[ty * 4 + i][c];
                ar[i] = fmaf(hv, wr, ar[i]);
                az[i] = fmaf(hv, wz, az[i]);
                an[i] = fmaf(hv, wn, an[i]);
            }
        }
        __syncthreads();
    }

    const int j = j0 + tx;
    const float br = bhh[j], bz = bhh[H_ + j], bn = bhh[2 * H_ + j];
#pragma unroll
    for (int i = 0; i < 4; ++i) {
        const int b = b0 + ty * 4 + i;
        const float* xrow = xg + ((long)b * T_ + tt) * G3H;
        const float xr = xrow[j], xz = xrow[H_ + j], xn = xrow[2 * H_ + j];
        const float hr = ar[i] + br, hz = az[i] + bz, hn = an[i] + bn;
        const float r = 1.f / (1.f + expf(-(xr + hr)));
        const float z = 1.f / (1.f + expf(-(xz + hz)));
        const float n = tanhf(xn + r * hn);
        const float hp = h_prev[(long)b * H_ + j];
        const float hnew = (1.f - z) * n + z * hp;
        const bool valid = tt < lengths[b];
        h_next[(long)b * H_ + j] = valid ? hnew : hp;
        gout[((long)b * T_ + tt) * H2 + dir * H_ + j] = valid ? hnew : 0.f;
    }
}

// mean over valid timesteps; outputs past length are already zero
__global__ void mean_pool(const float* __restrict__ gin,
                          const int* __restrict__ lengths,
                          float* __restrict__ mean)
{
    const int idx = blockIdx.x * 256 + threadIdx.x;   // B*2H
    const int b = idx >> 11, c = idx & 2047;
    float s = 0.f;
#pragma unroll
    for (int t = 0; t < T_; ++t) s += gin[((long)b * T_ + t) * H2 + c];
    mean[idx] = s / (float)lengths[b];
}

__global__ void fill_bias(float* __restrict__ Y, const float* __restrict__ bias, int rows)
{
    const int idx = blockIdx.x * 256 + threadIdx.x;
    if (idx < rows * NF_) Y[idx] = bias[idx & (NF_ - 1)];
}

__global__ void conv_max(const float* __restrict__ Y2, const float* __restrict__ Y3,
                         const float* __restrict__ Y4, float* __restrict__ out)
{
    const int idx = blockIdx.x * 256 + threadIdx.x;   // B*1536
    const int b = idx / 1536, u = idx % 1536;
    const float* Y; int Tout, f;
    if (u < 512)       { Y = Y2; Tout = 33; f = u; }
    else if (u < 1024) { Y = Y3; Tout = 34; f = u - 512; }
    else               { Y = Y4; Tout = 35; f = u - 1024; }
    float m = -INFINITY;
    for (int j = 0; j < Tout; ++j) {
        float v = Y[((long)b * Tout + j) * NF_ + f];
        v = v > 0.f ? v : 0.01f * v;
        m = fmaxf(m, v);
    }
    out[(long)b * OUTC + H_ + u] = m;
}

__global__ void bow_copy(const float* __restrict__ bow, float* __restrict__ out)
{
    const int idx = blockIdx.x * 256 + threadIdx.x;   // B * 2000 float4s
    const int b = idx / 2000, q = idx % 2000;
    const float4* src = (const float4*)(bow + (long)b * V_);
    float4* dst = (float4*)(out + (long)b * OUTC + H_ + 3 * NF_);
    dst[q] = src[q];
}

extern "C" void kernel_launch(void* const* d_in, const int* in_sizes, int n_in,
                              void* d_out, int out_size, void* d_ws, size_t ws_size,
                              hipStream_t stream)
{
    const float* text    = (const float*)d_in[0];
    const float* bow     = (const float*)d_in[1];
    const int*   lengths = (const int*)  d_in[2];
    const float* Wih_f   = (const float*)d_in[3];
    const float* Whh_f   = (const float*)d_in[4];
    const float* bih_f   = (const float*)d_in[5];
    const float* bhh_f   = (const float*)d_in[6];
    const float* Wih_b   = (const float*)d_in[7];
    const float* Whh_b   = (const float*)d_in[8];
    const float* bih_b   = (const float*)d_in[9];
    const float* bhh_b   = (const float*)d_in[10];
    const float* W_red   = (const float*)d_in[11];
    const float* b_red   = (const float*)d_in[12];
    const float* cw2     = (const float*)d_in[13];
    const float* cb2     = (const float*)d_in[14];
    const float* cw3     = (const float*)d_in[15];
    const float* cb3     = (const float*)d_in[16];
    const float* cw4     = (const float*)d_in[17];
    const float* cb4     = (const float*)d_in[18];
    float* out = (float*)d_out;

    float* ws = (float*)d_ws;
    size_t off = 0;
    float* xg    = ws + off; off += (size_t)B_ * T_ * G3H;   // 25,165,824
    float* gin   = ws + off; off += (size_t)B_ * T_ * H2;    // 16,777,216
    float* hf    = ws + off; off += 2 * (size_t)B_ * H_;
    float* hb    = ws + off; off += 2 * (size_t)B_ * H_;
    float* gmean = ws + off; off += (size_t)B_ * H2;
    // conv Y buffers overlay the (dead-by-then) xg region
    float* Y2 = xg;
    float* Y3 = Y2 + (size_t)B_ * 33 * NF_;
    float* Y4 = Y3 + (size_t)B_ * 34 * NF_;

    const dim3 blk(256);

    // zero the h ping-pong buffers (hf and hb are contiguous)
    hipMemsetAsync(hf, 0, (size_t)4 * B_ * H_ * sizeof(float), stream);

    // ---- forward direction ----
    gemm128<<<dim3(G3H / 128, (B_ * T_) / 128), blk, 0, stream>>>(
        text, D_, Wih_f, D_, 1, 0, bih_f, xg, G3H, D_, 0, 0, 0);
    for (int t = 0; t < T_; ++t)
        gru_step<<<dim3(H_ / 32, B_ / 32), blk, 0, stream>>>(
            xg, Whh_f, bhh_f, hf + (size_t)(t & 1) * B_ * H_,
            hf + (size_t)((t + 1) & 1) * B_ * H_, gin, lengths, t, 0);

    // ---- backward direction (reuses xg) ----
    gemm128<<<dim3(G3H / 128, (B_ * T_) / 128), blk, 0, stream>>>(
        text, D_, Wih_b, D_, 1, 0, bih_b, xg, G3H, D_, 0, 0, 0);
    for (int s = 0; s < T_; ++s)
        gru_step<<<dim3(H_ / 32, B_ / 32), blk, 0, stream>>>(
            xg, Whh_b, bhh_b, hb + (size_t)(s & 1) * B_ * H_,
            hb + (size_t)((s + 1) & 1) * B_ * H_, gin, lengths, T_ - 1 - s, 1);

    // ---- pooled linear head ----
    mean_pool<<<dim3((B_ * H2) / 256), blk, 0, stream>>>(gin, lengths, gmean);
    gemm128<<<dim3(H_ / 128, B_ / 128), blk, 0, stream>>>(
        gmean, H2, W_red, H2, 1, 0, b_red, out, OUTC, H2, 0, 0, 0);

    // ---- conv branches as shifted tap-GEMMs ----
    fill_bias<<<dim3((B_ * 33 * NF_ + 255) / 256), blk, 0, stream>>>(Y2, cb2, B_ * 33);
    fill_bias<<<dim3((B_ * 34 * NF_ + 255) / 256), blk, 0, stream>>>(Y3, cb3, B_ * 34);
    fill_bias<<<dim3((B_ * 35 * NF_ + 255) / 256), blk, 0, stream>>>(Y4, cb4, B_ * 35);

    for (int k = 0; k < 2; ++k)
        gemm128<<<dim3(NF_ / 128, (B_ * T_) / 128), blk, 0, stream>>>(
            gin, H2, cw2, (long)H2 * 2, 2, k, nullptr, Y2, 0, H2, 1, 33, 1 - k);
    for (int k = 0; k < 3; ++k)
        gemm128<<<dim3(NF_ / 128, (B_ * T_) / 128), blk, 0, stream>>>(
            gin, H2, cw3, (long)H2 * 3, 3, k, nullptr, Y3, 0, H2, 1, 34, 2 - k);
    for (int k = 0; k < 4; ++k)
        gemm128<<<dim3(NF_ / 128, (B_ * T_) / 128), blk, 0, stream>>>(
            gin, H2, cw4, (long)H2 * 4, 4, k, nullptr, Y4, 0, H2, 1, 35, 3 - k);

    conv_max<<<dim3((B_ * 1536) / 256), blk, 0, stream>>>(Y2, Y3, Y4, out);
    bow_copy<<<dim3((B_ * 2000) / 256), blk, 0, stream>>>(bow, out);
}

// Round 2
// 2947.825 us; speedup vs baseline: 4.3598x; 4.3598x over previous
//
#include <hip/hip_runtime.h>
#include <hip/hip_bf16.h>
#include <math.h>

#define B_ 256
#define T_ 32
#define D_ 500
#define H_ 1024
#define V_ 8000
#define NF_ 512
#define G3H (3*H_)   // 3072
#define H2 (2*H_)    // 2048
#define OUTC (H_ + 3*NF_ + V_)   // 10560
#define KPAD 512     // D_ padded to 512 for 16B-aligned bf16 rows

typedef float f32x4 __attribute__((ext_vector_type(4)));
typedef short bf16x8 __attribute__((ext_vector_type(8)));

static __device__ __forceinline__ short f2b(float f) {
    unsigned u = __float_as_uint(f);
    unsigned r = (u + 0x7fffu + ((u >> 16) & 1u)) >> 16;
    return (short)r;
}
static __device__ __forceinline__ float b2f(short s) {
    return __uint_as_float(((unsigned)(unsigned short)s) << 16);
}

// ---------------------------------------------------------------------------
// bf16 MFMA GEMM (m97 structure): C[m,n] = sum_k A[m,k] * Bt[n,k]
// A: [M x lda] bf16 row-major, Bt: [N x ldb] bf16 row-major (k contiguous).
// M,N multiples of 128; K multiple of 32; lda/ldb multiples of 8.
// mode 0: fp32 C[m*ldc+n] = v (+bias[n])
// mode 1: conv tap scatter:  Y[((m>>5)*Tout + (m&31) + sshift)*NF_ + n] += v
// mode 2: bf16 C[m*ldc+n] = bf16(v + bias[n])
// ---------------------------------------------------------------------------
__global__ __launch_bounds__(256) void gemm_bt(
    const short* __restrict__ A, int lda,
    const short* __restrict__ Bt, int ldb,
    const float* __restrict__ bias,
    void* __restrict__ Cv, int ldc,
    int K, int mode, int Tout, int sshift)
{
    __shared__ short As[128 * 32];
    __shared__ short Bs[128 * 32];
    const int tid  = threadIdx.x;
    const int w    = tid >> 6, lane = tid & 63;
    const int m0   = blockIdx.y * 128, n0 = blockIdx.x * 128;
    const int wm   = (w >> 1) * 64, wn = (w & 1) * 64;

    f32x4 acc[4][4];
#pragma unroll
    for (int i = 0; i < 4; ++i)
#pragma unroll
        for (int j = 0; j < 4; ++j) acc[i][j] = (f32x4){0.f, 0.f, 0.f, 0.f};

    // staging: round r (0,1), wave w covers tile rows [(r*4+w)*16, +16)
    const int srow = w * 16 + (lane >> 2);
    const int scol = (lane & 3) * 8;
    const long aoff0 = (long)(m0 + srow) * lda + scol;
    const long aoff1 = (long)(m0 + srow + 64) * lda + scol;
    const long boff0 = (long)(n0 + srow) * ldb + scol;
    const long boff1 = (long)(n0 + srow + 64) * ldb + scol;
    short* lA0 = As + w * 512;        short* lA1 = As + 2048 + w * 512;
    short* lB0 = Bs + w * 512;        short* lB1 = Bs + 2048 + w * 512;

    const int fr = lane & 15, fk = (lane >> 4) * 8;

    for (int kt = 0; kt < K; kt += 32) {
        __builtin_amdgcn_global_load_lds((const __attribute__((address_space(1))) void*)(A + aoff0 + kt),
                                         (__attribute__((address_space(3))) void*)lA0, 16, 0, 0);
        __builtin_amdgcn_global_load_lds((const __attribute__((address_space(1))) void*)(A + aoff1 + kt),
                                         (__attribute__((address_space(3))) void*)lA1, 16, 0, 0);
        __builtin_amdgcn_global_load_lds((const __attribute__((address_space(1))) void*)(Bt + boff0 + kt),
                                         (__attribute__((address_space(3))) void*)lB0, 16, 0, 0);
        __builtin_amdgcn_global_load_lds((const __attribute__((address_space(1))) void*)(Bt + boff1 + kt),
                                         (__attribute__((address_space(3))) void*)lB1, 16, 0, 0);
        __syncthreads();
        bf16x8 af[4], bfv[4];
#pragma unroll
        for (int i = 0; i < 4; ++i) af[i]  = *(const bf16x8*)(As + (wm + i * 16 + fr) * 32 + fk);
#pragma unroll
        for (int j = 0; j < 4; ++j) bfv[j] = *(const bf16x8*)(Bs + (wn + j * 16 + fr) * 32 + fk);
#pragma unroll
        for (int i = 0; i < 4; ++i)
#pragma unroll
            for (int j = 0; j < 4; ++j)
                acc[i][j] = __builtin_amdgcn_mfma_f32_16x16x32_bf16(af[i], bfv[j], acc[i][j], 0, 0, 0);
        __syncthreads();
    }

    const int er = (lane >> 4) * 4;   // C/D: col = lane&15, row = (lane>>4)*4 + q
    const int ec = lane & 15;
#pragma unroll
    for (int i = 0; i < 4; ++i) {
#pragma unroll
        for (int j = 0; j < 4; ++j) {
#pragma unroll
            for (int q = 0; q < 4; ++q) {
                const int m = m0 + wm + i * 16 + er + q;
                const int n = n0 + wn + j * 16 + ec;
                float v = acc[i][j][q];
                if (mode == 0) {
                    ((float*)Cv)[(long)m * ldc + n] = v + (bias ? bias[n] : 0.f);
                } else if (mode == 1) {
                    float* Y = (float*)Cv;
                    const long yi = ((long)((m >> 5) * Tout + (m & 31) + sshift)) * NF_ + n;
                    Y[yi] += v;
                } else {
                    ((short*)Cv)[(long)m * ldc + n] = f2b(v + (bias ? bias[n] : 0.f));
                }
            }
        }
    }
}

// ---------------------------------------------------------------------------
// fused GRU gate update (per timestep). hg = h_prev @ Whh^T (no bias) fp32.
// ---------------------------------------------------------------------------
__global__ __launch_bounds__(256) void gru_gate(
    const short* __restrict__ xg, const float* __restrict__ hg,
    const float* __restrict__ bhh, const float* __restrict__ h_prev,
    float* __restrict__ h_next, short* __restrict__ h_bf,
    short* __restrict__ gout, const int* __restrict__ lengths, int tt, int dir)
{
    const int idx = blockIdx.x * 256 + threadIdx.x;   // B*H
    const int b = idx >> 10, j = idx & 1023;
    const short* xrow = xg + ((long)(b * T_ + tt)) * G3H;
    const float xr = b2f(xrow[j]), xz = b2f(xrow[H_ + j]), xn = b2f(xrow[2 * H_ + j]);
    const float* hrow = hg + (long)b * G3H;
    const float hr = hrow[j] + bhh[j];
    const float hz = hrow[H_ + j] + bhh[H_ + j];
    const float hn = hrow[2 * H_ + j] + bhh[2 * H_ + j];
    const float r = 1.f / (1.f + expf(-(xr + hr)));
    const float z = 1.f / (1.f + expf(-(xz + hz)));
    const float n = tanhf(xn + r * hn);
    const float hp = h_prev[idx];
    const float hnew = (1.f - z) * n + z * hp;
    const bool valid = tt < lengths[b];
    const float ho = valid ? hnew : hp;
    h_next[idx] = ho;
    h_bf[idx]   = f2b(ho);
    gout[((long)(b * T_ + tt)) * H2 + dir * H_ + j] = valid ? f2b(hnew) : 0;
}

// fp32 -> bf16 with optional K padding (c >= Ksrc -> 0)
__global__ void f2b_pad(const float* __restrict__ src, short* __restrict__ dst,
                        int Ksrc, int Kdst)
{
    const int idx = blockIdx.x * 256 + threadIdx.x;   // rows*Kdst
    const int r = idx / Kdst, c = idx % Kdst;
    dst[idx] = (c < Ksrc) ? f2b(src[(long)r * Ksrc + c]) : (short)0;
}

// conv weight repack: dst[k][f][c] = bf16(src[f][c][k]), src [NF_,2H,ws]
__global__ void repack_tap(const float* __restrict__ src, short* __restrict__ dst, int ws)
{
    const int idx = blockIdx.x * 256 + threadIdx.x;   // ws*NF_*2048
    const int rem = idx % (NF_ * H2);
    const int k = idx / (NF_ * H2);
    const int f = rem >> 11, c = rem & 2047;
    dst[idx] = f2b(src[((long)(f << 11) + c) * ws + k]);
}

// mean over valid timesteps (gin is zero past length), bf16 in, fp32+bf16 out
__global__ void mean_pool(const short* __restrict__ gin,
                          const int* __restrict__ lengths,
                          float* __restrict__ mean, short* __restrict__ mean_bf)
{
    const int idx = blockIdx.x * 256 + threadIdx.x;   // B*2H
    const int b = idx >> 11, c = idx & 2047;
    float s = 0.f;
#pragma unroll
    for (int t = 0; t < T_; ++t) s += b2f(gin[((long)(b * T_ + t)) * H2 + c]);
    const float m = s / (float)lengths[b];
    mean[idx] = m;
    mean_bf[idx] = f2b(m);
}

__global__ void conv_max(const float* __restrict__ Y2, const float* __restrict__ Y3,
                         const float* __restrict__ Y4,
                         const float* __restrict__ cb2, const float* __restrict__ cb3,
                         const float* __restrict__ cb4, float* __restrict__ out)
{
    const int idx = blockIdx.x * 256 + threadIdx.x;   // B*1536
    const int b = idx / 1536, u = idx % 1536;
    const float* Y; int Tout, f; float bias;
    if (u < 512)       { Y = Y2; Tout = 33; f = u;        bias = cb2[f]; }
    else if (u < 1024) { Y = Y3; Tout = 34; f = u - 512;  bias = cb3[f]; }
    else               { Y = Y4; Tout = 35; f = u - 1024; bias = cb4[f]; }
    float m = -INFINITY;
    for (int j = 0; j < Tout; ++j) {
        float v = Y[((long)(b * Tout + j)) * NF_ + f] + bias;
        v = v > 0.f ? v : 0.01f * v;
        m = fmaxf(m, v);
    }
    out[(long)b * OUTC + H_ + u] = m;
}

__global__ void bow_copy(const float* __restrict__ bow, float* __restrict__ out)
{
    const int idx = blockIdx.x * 256 + threadIdx.x;   // B * 2000 float4s
    const int b = idx / 2000, q = idx % 2000;
    const float4* src = (const float4*)(bow + (long)b * V_);
    float4* dst = (float4*)(out + (long)b * OUTC + H_ + 3 * NF_);
    dst[q] = src[q];
}

extern "C" void kernel_launch(void* const* d_in, const int* in_sizes, int n_in,
                              void* d_out, int out_size, void* d_ws, size_t ws_size,
                              hipStream_t stream)
{
    const float* text    = (const float*)d_in[0];
    const float* bow     = (const float*)d_in[1];
    const int*   lengths = (const int*)  d_in[2];
    const float* Wih_f   = (const float*)d_in[3];
    const float* Whh_f   = (const float*)d_in[4];
    const float* bih_f   = (const float*)d_in[5];
    const float* bhh_f   = (const float*)d_in[6];
    const float* Wih_b   = (const float*)d_in[7];
    const float* Whh_b   = (const float*)d_in[8];
    const float* bih_b   = (const float*)d_in[9];
    const float* bhh_b   = (const float*)d_in[10];
    const float* W_red   = (const float*)d_in[11];
    const float* b_red   = (const float*)d_in[12];
    const float* cw2     = (const float*)d_in[13];
    const float* cb2     = (const float*)d_in[14];
    const float* cw3     = (const float*)d_in[15];
    const float* cb3     = (const float*)d_in[16];
    const float* cw4     = (const float*)d_in[17];
    const float* cb4     = (const float*)d_in[18];
    float* out = (float*)d_out;

    // ---- workspace layout (bytes) ----
    char* ws = (char*)d_ws;
    size_t off = 0;
    short* xg_bf   = (short*)(ws + off); off += (size_t)B_ * T_ * G3H * 2;   // 50.3 MB
    short* text_bf = (short*)(ws + off); off += (size_t)B_ * T_ * KPAD * 2;  // 8.4 MB (dead after proj)
    short* gin_bf  = (short*)(ws + off); off += (size_t)B_ * T_ * H2 * 2;    // 33.6 MB
    short* wihf_bf = (short*)(ws + off); off += (size_t)G3H * KPAD * 2;
    short* wihb_bf = (short*)(ws + off); off += (size_t)G3H * KPAD * 2;
    short* whhf_bf = (short*)(ws + off); off += (size_t)G3H * H_ * 2;
    short* whhb_bf = (short*)(ws + off); off += (size_t)G3H * H_ * 2;
    short* wred_bf = (short*)(ws + off); off += (size_t)H_ * H2 * 2;
    short* wtap_bf = (short*)(ws + off); off += (size_t)9 * NF_ * H2 * 2;    // 18.9 MB
    float* h       = (float*)(ws + off); off += (size_t)2 * B_ * H_ * 4;     // ping-pong
    short* h_bf    = (short*)(ws + off); off += (size_t)B_ * H_ * 2;         // contiguous w/ h
    float* hg      = (float*)(ws + off); off += (size_t)B_ * G3H * 4;
    float* gmean   = (float*)(ws + off); off += (size_t)B_ * H2 * 4;
    short* gmean_bf= (short*)(ws + off); off += (size_t)B_ * H2 * 2;
    // conv Y buffers overlay xg_bf + text_bf (dead by conv phase): 53.5 MB <= 58.7 MB
    float* Y2 = (float*)d_ws;
    float* Y3 = Y2 + (size_t)B_ * 33 * NF_;
    float* Y4 = Y3 + (size_t)B_ * 34 * NF_;

    const dim3 blk(256);

    // ---- weight/input conversions (bf16) ----
    f2b_pad<<<dim3((B_ * T_ * KPAD) / 256), blk, 0, stream>>>(text, text_bf, D_, KPAD);
    f2b_pad<<<dim3((G3H * KPAD) / 256), blk, 0, stream>>>(Wih_f, wihf_bf, D_, KPAD);
    f2b_pad<<<dim3((G3H * KPAD) / 256), blk, 0, stream>>>(Wih_b, wihb_bf, D_, KPAD);
    f2b_pad<<<dim3((G3H * H_) / 256), blk, 0, stream>>>(Whh_f, whhf_bf, H_, H_);
    f2b_pad<<<dim3((G3H * H_) / 256), blk, 0, stream>>>(Whh_b, whhb_bf, H_, H_);
    f2b_pad<<<dim3((H_ * H2) / 256), blk, 0, stream>>>(W_red, wred_bf, H2, H2);
    repack_tap<<<dim3((2 * NF_ * H2) / 256), blk, 0, stream>>>(cw2, wtap_bf, 2);
    repack_tap<<<dim3((3 * NF_ * H2) / 256), blk, 0, stream>>>(cw3, wtap_bf + (size_t)2 * NF_ * H2, 3);
    repack_tap<<<dim3((4 * NF_ * H2) / 256), blk, 0, stream>>>(cw4, wtap_bf + (size_t)5 * NF_ * H2, 4);

    // ---- forward direction ----
    gemm_bt<<<dim3(G3H / 128, (B_ * T_) / 128), blk, 0, stream>>>(
        text_bf, KPAD, wihf_bf, KPAD, bih_f, xg_bf, G3H, KPAD, 2, 0, 0);
    hipMemsetAsync(h, 0, (size_t)2 * B_ * H_ * 4 + (size_t)B_ * H_ * 2, stream);
    for (int t = 0; t < T_; ++t) {
        gemm_bt<<<dim3(G3H / 128, B_ / 128), blk, 0, stream>>>(
            h_bf, H_, whhf_bf, H_, nullptr, hg, G3H, H_, 0, 0, 0);
        gru_gate<<<dim3((B_ * H_) / 256), blk, 0, stream>>>(
            xg_bf, hg, bhh_f, h + (size_t)(t & 1) * B_ * H_,
            h + (size_t)((t + 1) & 1) * B_ * H_, h_bf, gin_bf, lengths, t, 0);
    }

    // ---- backward direction (reuses xg_bf) ----
    gemm_bt<<<dim3(G3H / 128, (B_ * T_) / 128), blk, 0, stream>>>(
        text_bf, KPAD, wihb_bf, KPAD, bih_b, xg_bf, G3H, KPAD, 2, 0, 0);
    hipMemsetAsync(h, 0, (size_t)2 * B_ * H_ * 4 + (size_t)B_ * H_ * 2, stream);
    for (int s = 0; s < T_; ++s) {
        gemm_bt<<<dim3(G3H / 128, B_ / 128), blk, 0, stream>>>(
            h_bf, H_, whhb_bf, H_, nullptr, hg, G3H, H_, 0, 0, 0);
        gru_gate<<<dim3((B_ * H_) / 256), blk, 0, stream>>>(
            xg_bf, hg, bhh_b, h + (size_t)(s & 1) * B_ * H_,
            h + (size_t)((s + 1) & 1) * B_ * H_, h_bf, gin_bf, lengths, T_ - 1 - s, 1);
    }

    // ---- pooled linear head ----
    mean_pool<<<dim3((B_ * H2) / 256), blk, 0, stream>>>(gin_bf, lengths, gmean, gmean_bf);
    gemm_bt<<<dim3(H_ / 128, B_ / 128), blk, 0, stream>>>(
        gmean_bf, H2, wred_bf, H2, b_red, out, OUTC, H2, 0, 0, 0);

    // ---- conv branches as shifted tap-GEMMs (Y zero-init, bias in conv_max) ----
    hipMemsetAsync(Y2, 0, (size_t)B_ * (33 + 34 + 35) * NF_ * 4, stream);
    for (int k = 0; k < 2; ++k)
        gemm_bt<<<dim3(NF_ / 128, (B_ * T_) / 128), blk, 0, stream>>>(
            gin_bf, H2, wtap_bf + (size_t)(0 + k) * NF_ * H2, H2, nullptr, Y2, 0, H2, 1, 33, 1 - k);
    for (int k = 0; k < 3; ++k)
        gemm_bt<<<dim3(NF_ / 128, (B_ * T_) / 128), blk, 0, stream>>>(
            gin_bf, H2, wtap_bf + (size_t)(2 + k) * NF_ * H2, H2, nullptr, Y3, 0, H2, 1, 34, 2 - k);
    for (int k = 0; k < 4; ++k)
        gemm_bt<<<dim3(NF_ / 128, (B_ * T_) / 128), blk, 0, stream>>>(
            gin_bf, H2, wtap_bf + (size_t)(5 + k) * NF_ * H2, H2, nullptr, Y4, 0, H2, 1, 35, 3 - k);

    conv_max<<<dim3((B_ * 1536) / 256), blk, 0, stream>>>(Y2, Y3, Y4, cb2, cb3, cb4, out);
    bow_copy<<<dim3((B_ * 2000) / 256), blk, 0, stream>>>(bow, out);
}

// Round 3
// 1319.216 us; speedup vs baseline: 9.7421x; 2.2345x over previous
//
#include <hip/hip_runtime.h>
#include <hip/hip_bf16.h>
#include <math.h>

#define B_ 256
#define T_ 32
#define D_ 500
#define H_ 1024
#define V_ 8000
#define NF_ 512
#define G3H (3*H_)   // 3072
#define H2 (2*H_)    // 2048
#define OUTC (H_ + 3*NF_ + V_)   // 10560
#define KPAD 512     // D_ padded to 512 for 16B-aligned bf16 rows
#define NTAP 9
#define NCAT (NTAP*NF_)  // 4608
#define MS 512           // stacked M for recurrence (fwd 0..255, bwd 256..511)

typedef float f32x4 __attribute__((ext_vector_type(4)));
typedef short bf16x8 __attribute__((ext_vector_type(8)));

static __device__ __forceinline__ short f2b(float f) {
    unsigned u = __float_as_uint(f);
    unsigned r = (u + 0x7fffu + ((u >> 16) & 1u)) >> 16;
    return (short)r;
}
static __device__ __forceinline__ float b2f(short s) {
    return __uint_as_float(((unsigned)(unsigned short)s) << 16);
}

// ---------------------------------------------------------------------------
// bf16 MFMA GEMM (m97 structure): C[m,n] = sum_k A[m,k] * Bt[n,k]
// mode 0: fp32 C[m*ldc+n] = v + bias[n]
// mode 2: bf16 C[m*ldc+n] = bf16(v + bias[n])
// mode 3: fp16 C[m*ldc+n] = fp16(v)           (tap partials)
// ---------------------------------------------------------------------------
__global__ __launch_bounds__(256) void gemm_bt(
    const short* __restrict__ A, int lda,
    const short* __restrict__ Bt, int ldb,
    const float* __restrict__ bias,
    void* __restrict__ Cv, int ldc,
    int K, int mode)
{
    __shared__ short As[128 * 32];
    __shared__ short Bs[128 * 32];
    const int tid  = threadIdx.x;
    const int w    = tid >> 6, lane = tid & 63;
    const int m0   = blockIdx.y * 128, n0 = blockIdx.x * 128;
    const int wm   = (w >> 1) * 64, wn = (w & 1) * 64;

    f32x4 acc[4][4];
#pragma unroll
    for (int i = 0; i < 4; ++i)
#pragma unroll
        for (int j = 0; j < 4; ++j) acc[i][j] = (f32x4){0.f, 0.f, 0.f, 0.f};

    const int srow = w * 16 + (lane >> 2);
    const int scol = (lane & 3) * 8;
    const long aoff0 = (long)(m0 + srow) * lda + scol;
    const long aoff1 = (long)(m0 + srow + 64) * lda + scol;
    const long boff0 = (long)(n0 + srow) * ldb + scol;
    const long boff1 = (long)(n0 + srow + 64) * ldb + scol;
    short* lA0 = As + w * 512;        short* lA1 = As + 2048 + w * 512;
    short* lB0 = Bs + w * 512;        short* lB1 = Bs + 2048 + w * 512;

    const int fr = lane & 15, fk = (lane >> 4) * 8;

    for (int kt = 0; kt < K; kt += 32) {
        __builtin_amdgcn_global_load_lds((const __attribute__((address_space(1))) void*)(A + aoff0 + kt),
                                         (__attribute__((address_space(3))) void*)lA0, 16, 0, 0);
        __builtin_amdgcn_global_load_lds((const __attribute__((address_space(1))) void*)(A + aoff1 + kt),
                                         (__attribute__((address_space(3))) void*)lA1, 16, 0, 0);
        __builtin_amdgcn_global_load_lds((const __attribute__((address_space(1))) void*)(Bt + boff0 + kt),
                                         (__attribute__((address_space(3))) void*)lB0, 16, 0, 0);
        __builtin_amdgcn_global_load_lds((const __attribute__((address_space(1))) void*)(Bt + boff1 + kt),
                                         (__attribute__((address_space(3))) void*)lB1, 16, 0, 0);
        __syncthreads();
        bf16x8 af[4], bfv[4];
#pragma unroll
        for (int i = 0; i < 4; ++i) af[i]  = *(const bf16x8*)(As + (wm + i * 16 + fr) * 32 + fk);
#pragma unroll
        for (int j = 0; j < 4; ++j) bfv[j] = *(const bf16x8*)(Bs + (wn + j * 16 + fr) * 32 + fk);
#pragma unroll
        for (int i = 0; i < 4; ++i)
#pragma unroll
            for (int j = 0; j < 4; ++j)
                acc[i][j] = __builtin_amdgcn_mfma_f32_16x16x32_bf16(af[i], bfv[j], acc[i][j], 0, 0, 0);
        __syncthreads();
    }

    const int er = (lane >> 4) * 4;   // C/D: col = lane&15, row = (lane>>4)*4 + q
    const int ec = lane & 15;
#pragma unroll
    for (int i = 0; i < 4; ++i) {
#pragma unroll
        for (int j = 0; j < 4; ++j) {
#pragma unroll
            for (int q = 0; q < 4; ++q) {
                const int m = m0 + wm + i * 16 + er + q;
                const int n = n0 + wn + j * 16 + ec;
                float v = acc[i][j][q];
                if (mode == 0) {
                    ((float*)Cv)[(long)m * ldc + n] = v + bias[n];
                } else if (mode == 2) {
                    ((short*)Cv)[(long)m * ldc + n] = f2b(v + bias[n]);
                } else {
                    ((_Float16*)Cv)[(long)m * ldc + n] = (_Float16)v;
                }
            }
        }
    }
}

// ---------------------------------------------------------------------------
// One GRU timestep, both directions stacked (M=512), gates fused in epilogue.
// Block: 64 m-rows x 64 j-cols, computes r/z/n (3 gates) for its tile.
// Grid: (H/64=16, MS/64=8), 256 threads (4 waves as 2x2 of 32x32).
// ---------------------------------------------------------------------------
__global__ __launch_bounds__(256) void gru_step_mfma(
    const short* __restrict__ h_bf_prev, short* __restrict__ h_bf_next,
    const float* __restrict__ h_prev, float* __restrict__ h_next,
    const short* __restrict__ whhf, const short* __restrict__ whhb,
    const float* __restrict__ bhhf, const float* __restrict__ bhhb,
    const short* __restrict__ xgf, const short* __restrict__ xgb,
    short* __restrict__ gout, const int* __restrict__ lengths, int s)
{
    __shared__ short As[64 * 32];
    __shared__ short Bs[3 * 64 * 32];
    const int tid = threadIdx.x;
    const int w = tid >> 6, lane = tid & 63;
    const int j0 = blockIdx.x * 64, m0 = blockIdx.y * 64;
    const int dir = (m0 >= 256) ? 1 : 0;
    const int wm = (w >> 1) * 32, wn = (w & 1) * 32;

    const short* whh = dir ? whhb : whhf;
    const float* bhh = dir ? bhhb : bhhf;
    const short* xg  = dir ? xgb : xgf;
    const int tt = dir ? (T_ - 1 - s) : s;

    f32x4 acc[3][2][2];
#pragma unroll
    for (int g = 0; g < 3; ++g)
#pragma unroll
        for (int i = 0; i < 2; ++i)
#pragma unroll
            for (int j = 0; j < 2; ++j) acc[g][i][j] = (f32x4){0.f, 0.f, 0.f, 0.f};

    const int srow = w * 16 + (lane >> 2);
    const int scol = (lane & 3) * 8;
    const long aoff = (long)(m0 + srow) * H_ + scol;
    const long boffr = (long)(j0 + srow) * H_ + scol;
    short* lA = As + w * 512;
    const int fr = lane & 15, fk = (lane >> 4) * 8;

    for (int kt = 0; kt < H_; kt += 32) {
        __builtin_amdgcn_global_load_lds((const __attribute__((address_space(1))) void*)(h_bf_prev + aoff + kt),
                                         (__attribute__((address_space(3))) void*)lA, 16, 0, 0);
#pragma unroll
        for (int g = 0; g < 3; ++g)
            __builtin_amdgcn_global_load_lds((const __attribute__((address_space(1))) void*)(whh + (long)g * H_ * H_ + boffr + kt),
                                             (__attribute__((address_space(3))) void*)(Bs + g * 2048 + w * 512), 16, 0, 0);
        __syncthreads();
        bf16x8 af[2], bfv[3][2];
#pragma unroll
        for (int i = 0; i < 2; ++i) af[i] = *(const bf16x8*)(As + (wm + i * 16 + fr) * 32 + fk);
#pragma unroll
        for (int g = 0; g < 3; ++g)
#pragma unroll
            for (int j = 0; j < 2; ++j) bfv[g][j] = *(const bf16x8*)(Bs + g * 2048 + (wn + j * 16 + fr) * 32 + fk);
#pragma unroll
        for (int g = 0; g < 3; ++g)
#pragma unroll
            for (int i = 0; i < 2; ++i)
#pragma unroll
                for (int j = 0; j < 2; ++j)
                    acc[g][i][j] = __builtin_amdgcn_mfma_f32_16x16x32_bf16(af[i], bfv[g][j], acc[g][i][j], 0, 0, 0);
        __syncthreads();
    }

    const int er = (lane >> 4) * 4;
    const int ec = lane & 15;
#pragma unroll
    for (int i = 0; i < 2; ++i) {
#pragma unroll
        for (int j = 0; j < 2; ++j) {
#pragma unroll
            for (int q = 0; q < 4; ++q) {
                const int m = m0 + wm + i * 16 + er + q;
                const int jj = j0 + wn + j * 16 + ec;
                const int b = m & 255;
                const short* xrow = xg + ((long)(b * T_ + tt)) * G3H;
                const float xr = b2f(xrow[jj]);
                const float xz = b2f(xrow[H_ + jj]);
                const float xn = b2f(xrow[2 * H_ + jj]);
                const float hr = acc[0][i][j][q] + bhh[jj];
                const float hz = acc[1][i][j][q] + bhh[H_ + jj];
                const float hn = acc[2][i][j][q] + bhh[2 * H_ + jj];
                const float r = 1.f / (1.f + expf(-(xr + hr)));
                const float z = 1.f / (1.f + expf(-(xz + hz)));
                const float n = tanhf(xn + r * hn);
                const long hidx = (long)m * H_ + jj;
                const float hp = h_prev[hidx];
                const float hnew = (1.f - z) * n + z * hp;
                const bool valid = tt < lengths[b];
                const float ho = valid ? hnew : hp;
                h_next[hidx] = ho;
                h_bf_next[hidx] = f2b(ho);
                gout[((long)(b * T_ + tt)) * H2 + dir * H_ + jj] = valid ? f2b(hnew) : 0;
            }
        }
    }
}

// fp32 -> bf16 with optional K padding (c >= Ksrc -> 0)
__global__ void f2b_pad(const float* __restrict__ src, short* __restrict__ dst,
                        int Ksrc, int Kdst)
{
    const int idx = blockIdx.x * 256 + threadIdx.x;
    const int r = idx / Kdst, c = idx % Kdst;
    dst[idx] = (c < Ksrc) ? f2b(src[(long)r * Ksrc + c]) : (short)0;
}

// conv weight repack: dst[k][f][c] = bf16(src[f][c][k]), src [NF_,2H,ws]
__global__ void repack_tap(const float* __restrict__ src, short* __restrict__ dst, int ws)
{
    const int idx = blockIdx.x * 256 + threadIdx.x;
    const int rem = idx % (NF_ * H2);
    const int k = idx / (NF_ * H2);
    const int f = rem >> 11, c = rem & 2047;
    dst[idx] = f2b(src[((long)(f << 11) + c) * ws + k]);
}

// mean over valid timesteps (gin is zero past length), bf16 in, bf16 out
__global__ void mean_pool(const short* __restrict__ gin,
                          const int* __restrict__ lengths,
                          short* __restrict__ mean_bf)
{
    const int idx = blockIdx.x * 256 + threadIdx.x;   // B*2H
    const int b = idx >> 11;
    float s = 0.f;
#pragma unroll
    for (int t = 0; t < T_; ++t) s += b2f(gin[(long)idx + (long)t * H2 + 0 * (long)b]);
    // note: gin row stride per t for fixed (b,c) is H2; base = b*T_*H2 + c = computed via idx decomposition
    mean_bf[idx] = 0;  // overwritten below (kept simple); see real impl in mean_pool2
}

// real mean pool
__global__ void mean_pool2(const short* __restrict__ gin,
                           const int* __restrict__ lengths,
                           short* __restrict__ mean_bf)
{
    const int idx = blockIdx.x * 256 + threadIdx.x;   // B*2H
    const int b = idx >> 11, c = idx & 2047;
    float s = 0.f;
#pragma unroll
    for (int t = 0; t < T_; ++t) s += b2f(gin[((long)(b * T_ + t)) * H2 + c]);
    mean_bf[idx] = f2b(s / (float)lengths[b]);
}

// shifted tap-sum + bias + leaky-relu + max over time
__global__ void conv_max(const _Float16* __restrict__ P,
                         const float* __restrict__ cb2, const float* __restrict__ cb3,
                         const float* __restrict__ cb4, float* __restrict__ out)
{
    const int idx = blockIdx.x * 256 + threadIdx.x;   // B*1536
    const int b = idx / 1536, u0 = idx % 1536;
    int Tout, ws, base, f; float bias;
    if (u0 < 512)       { ws = 2; Tout = 33; base = 0;    f = u0;        bias = cb2[f]; }
    else if (u0 < 1024) { ws = 3; Tout = 34; base = 1024; f = u0 - 512;  bias = cb3[f]; }
    else                { ws = 4; Tout = 35; base = 2560; f = u0 - 1024; bias = cb4[f]; }
    const _Float16* Pb = P + (long)b * T_ * NCAT + base + f;
    float m = -INFINITY;
    for (int u = 0; u < Tout; ++u) {
        float s = bias;
        for (int k = 0; k < ws; ++k) {
            const int t = u - (ws - 1) + k;
            if (t >= 0 && t < T_) s += (float)Pb[(long)t * NCAT + k * NF_];
        }
        s = s > 0.f ? s : 0.01f * s;
        m = fmaxf(m, s);
    }
    out[(long)b * OUTC + H_ + u0] = m;
}

__global__ void bow_copy(const float* __restrict__ bow, float* __restrict__ out)
{
    const int idx = blockIdx.x * 256 + threadIdx.x;   // B * 2000 float4s
    const int b = idx / 2000, q = idx % 2000;
    const float4* src = (const float4*)(bow + (long)b * V_);
    float4* dst = (float4*)(out + (long)b * OUTC + H_ + 3 * NF_);
    dst[q] = src[q];
}

extern "C" void kernel_launch(void* const* d_in, const int* in_sizes, int n_in,
                              void* d_out, int out_size, void* d_ws, size_t ws_size,
                              hipStream_t stream)
{
    const float* text    = (const float*)d_in[0];
    const float* bow     = (const float*)d_in[1];
    const int*   lengths = (const int*)  d_in[2];
    const float* Wih_f   = (const float*)d_in[3];
    const float* Whh_f   = (const float*)d_in[4];
    const float* bih_f   = (const float*)d_in[5];
    const float* bhh_f   = (const float*)d_in[6];
    const float* Wih_b   = (const float*)d_in[7];
    const float* Whh_b   = (const float*)d_in[8];
    const float* bih_b   = (const float*)d_in[9];
    const float* bhh_b   = (const float*)d_in[10];
    const float* W_red   = (const float*)d_in[11];
    const float* b_red   = (const float*)d_in[12];
    const float* cw2     = (const float*)d_in[13];
    const float* cb2     = (const float*)d_in[14];
    const float* cw3     = (const float*)d_in[15];
    const float* cb3     = (const float*)d_in[16];
    const float* cw4     = (const float*)d_in[17];
    const float* cb4     = (const float*)d_in[18];
    float* out = (float*)d_out;

    // ---- workspace layout ----
    char* ws = (char*)d_ws;
    size_t off = 0;
    // xg region (100.66 MB): later overlaid by P (75.5 MB) + wtap (18.9 MB)
    short* xg_f = (short*)(ws + off); off += (size_t)B_ * T_ * G3H * 2;
    short* xg_b = (short*)(ws + off); off += (size_t)B_ * T_ * G3H * 2;
    _Float16* P   = (_Float16*)(char*)xg_f;                       // 8192 x 4608 fp16
    short* wtap_bf = (short*)((char*)xg_f + (size_t)B_ * T_ * NCAT * 2);  // after P
    // gin region (33.55 MB): text_bf + wih overlays (dead before first gout write)
    short* gin_bf = (short*)(ws + off); off += (size_t)B_ * T_ * H2 * 2;
    short* text_bf = gin_bf;
    short* wihf_bf = (short*)((char*)gin_bf + (size_t)B_ * T_ * KPAD * 2);
    short* wihb_bf = wihf_bf + (size_t)G3H * KPAD;
    // persistent weights
    short* whhf_bf = (short*)(ws + off); off += (size_t)G3H * H_ * 2;
    short* whhb_bf = (short*)(ws + off); off += (size_t)G3H * H_ * 2;
    short* wred_bf = (short*)(ws + off); off += (size_t)H_ * H2 * 2;
    // recurrence state (ping-pong)
    float* h      = (float*)(ws + off); off += (size_t)2 * MS * H_ * 4;
    short* h_bf   = (short*)(ws + off); off += (size_t)2 * MS * H_ * 2;
    short* gmean_bf = (short*)(ws + off); off += (size_t)B_ * H2 * 2;

    const dim3 blk(256);

    // ---- conversions ----
    f2b_pad<<<dim3((B_ * T_ * KPAD) / 256), blk, 0, stream>>>(text, text_bf, D_, KPAD);
    f2b_pad<<<dim3((G3H * KPAD) / 256), blk, 0, stream>>>(Wih_f, wihf_bf, D_, KPAD);
    f2b_pad<<<dim3((G3H * KPAD) / 256), blk, 0, stream>>>(Wih_b, wihb_bf, D_, KPAD);
    f2b_pad<<<dim3((G3H * H_) / 256), blk, 0, stream>>>(Whh_f, whhf_bf, H_, H_);
    f2b_pad<<<dim3((G3H * H_) / 256), blk, 0, stream>>>(Whh_b, whhb_bf, H_, H_);
    f2b_pad<<<dim3((H_ * H2) / 256), blk, 0, stream>>>(W_red, wred_bf, H2, H2);

    // ---- input projections (both directions) ----
    gemm_bt<<<dim3(G3H / 128, (B_ * T_) / 128), blk, 0, stream>>>(
        text_bf, KPAD, wihf_bf, KPAD, bih_f, xg_f, G3H, KPAD, 2);
    gemm_bt<<<dim3(G3H / 128, (B_ * T_) / 128), blk, 0, stream>>>(
        text_bf, KPAD, wihb_bf, KPAD, bih_b, xg_b, G3H, KPAD, 2);

    // ---- stacked bidirectional recurrence (32 fused steps) ----
    hipMemsetAsync(h, 0, (size_t)2 * MS * H_ * 4 + (size_t)2 * MS * H_ * 2, stream);
    for (int s = 0; s < T_; ++s) {
        const int cur = s & 1, nxt = (s + 1) & 1;
        gru_step_mfma<<<dim3(H_ / 64, MS / 64), blk, 0, stream>>>(
            h_bf + (size_t)cur * MS * H_, h_bf + (size_t)nxt * MS * H_,
            h + (size_t)cur * MS * H_, h + (size_t)nxt * MS * H_,
            whhf_bf, whhb_bf, bhh_f, bhh_b, xg_f, xg_b, gin_bf, lengths, s);
    }

    // ---- pooled linear head ----
    mean_pool2<<<dim3((B_ * H2) / 256), blk, 0, stream>>>(gin_bf, lengths, gmean_bf);
    gemm_bt<<<dim3(H_ / 128, B_ / 128), blk, 0, stream>>>(
        gmean_bf, H2, wred_bf, H2, b_red, out, OUTC, H2, 0);

    // ---- conv: repack taps (xg dead), one big GEMM -> fp16 partials ----
    repack_tap<<<dim3((2 * NF_ * H2) / 256), blk, 0, stream>>>(cw2, wtap_bf, 2);
    repack_tap<<<dim3((3 * NF_ * H2) / 256), blk, 0, stream>>>(cw3, wtap_bf + (size_t)2 * NF_ * H2, 3);
    repack_tap<<<dim3((4 * NF_ * H2) / 256), blk, 0, stream>>>(cw4, wtap_bf + (size_t)5 * NF_ * H2, 4);
    gemm_bt<<<dim3(NCAT / 128, (B_ * T_) / 128), blk, 0, stream>>>(
        gin_bf, H2, wtap_bf, H2, nullptr, P, NCAT, H2, 3);

    conv_max<<<dim3((B_ * 1536) / 256), blk, 0, stream>>>(P, cb2, cb3, cb4, out);
    bow_copy<<<dim3((B_ * 2000) / 256), blk, 0, stream>>>(bow, out);
}